// Round 1
// baseline (337.519 us; speedup 1.0000x reference)
//
#include <hip/hip_runtime.h>

// LSTM: B=4096 sequences, T=2048 steps, H=4, input dim 1, + linear head to 1.
// Strategy: one QUAD of lanes per sequence. Lane j owns h[j], c[j] and gate
// rows {j, 4+j, 8+j, 12+j} (PyTorch gate order i,f,g,o). All cross-lane
// communication (h broadcast, y reduction) is intra-quad via DPP quad_perm.
// Activation scales (log2 e) are pre-folded into the weights so each
// sigmoid/tanh is exp2 + add + rcp (+fma for tanh).

#define L2E 1.44269504088896340736f

constexpr int TLEN = 2048;

template <int CTRL>
__device__ __forceinline__ float qperm(float v) {
    return __int_as_float(
        __builtin_amdgcn_mov_dpp(__float_as_int(v), CTRL, 0xF, 0xF, true));
}

__device__ __forceinline__ float fexp2(float x) { return __builtin_amdgcn_exp2f(x); }
__device__ __forceinline__ float frcp(float x) { return __builtin_amdgcn_rcpf(x); }

__global__ __launch_bounds__(64) void lstm4_kernel(
    const float* __restrict__ x,      // [B, T]
    const float* __restrict__ W_ih,   // [16, 1]
    const float* __restrict__ W_hh,   // [16, 4]
    const float* __restrict__ b_ih,   // [16]
    const float* __restrict__ b_hh,   // [16]
    const float* __restrict__ W_lin,  // [1, 4]
    const float* __restrict__ b_lin,  // [1]
    float* __restrict__ out)          // [B, T]
{
    const int tid = blockIdx.x * 64 + threadIdx.x;
    const int seq = tid >> 2;
    const int j   = tid & 3;

    // Gate rows for this lane's column j.
    const int ri = j, rf = 4 + j, rg = 8 + j, ro = 12 + j;
    // Fold activation scaling into weights:
    //  sigmoid(z) = 1/(1+exp2(-z*L2E))  -> scale i,f,o rows by -L2E
    //  tanh(z)    = 1-2/(1+exp2(2z*L2E))-> scale g row by +2*L2E
    const float si = -L2E, sf = -L2E, sg = 2.0f * L2E, so = -L2E;

    const float wih_i = W_ih[ri] * si;
    const float wih_f = W_ih[rf] * sf;
    const float wih_g = W_ih[rg] * sg;
    const float wih_o = W_ih[ro] * so;

    const float bi = (b_ih[ri] + b_hh[ri]) * si;
    const float bf = (b_ih[rf] + b_hh[rf]) * sf;
    const float bg = (b_ih[rg] + b_hh[rg]) * sg;
    const float bo = (b_ih[ro] + b_hh[ro]) * so;

    const float wi0 = W_hh[ri * 4 + 0] * si, wi1 = W_hh[ri * 4 + 1] * si,
                wi2 = W_hh[ri * 4 + 2] * si, wi3 = W_hh[ri * 4 + 3] * si;
    const float wf0 = W_hh[rf * 4 + 0] * sf, wf1 = W_hh[rf * 4 + 1] * sf,
                wf2 = W_hh[rf * 4 + 2] * sf, wf3 = W_hh[rf * 4 + 3] * sf;
    const float wg0 = W_hh[rg * 4 + 0] * sg, wg1 = W_hh[rg * 4 + 1] * sg,
                wg2 = W_hh[rg * 4 + 2] * sg, wg3 = W_hh[rg * 4 + 3] * sg;
    const float wo0 = W_hh[ro * 4 + 0] * so, wo1 = W_hh[ro * 4 + 1] * so,
                wo2 = W_hh[ro * 4 + 2] * so, wo3 = W_hh[ro * 4 + 3] * so;

    const float wlin = W_lin[j];
    const float blin = b_lin[0];

    const float* xp = x + (size_t)seq * TLEN;
    float*       op = out + (size_t)seq * TLEN;

    float h = 0.0f, c = 0.0f;

    // Software-pipelined x stream: 8 steps (2x float4) per group, prefetched
    // one group ahead so the HBM latency (~900 cyc) hides under ~1000 cyc of
    // compute.
    float4 xa = *(const float4*)(xp);
    float4 xb = *(const float4*)(xp + 4);

    for (int t = 0; t < TLEN; t += 8) {
        int tn = t + 8;
        if (tn > TLEN - 8) tn = 0;  // safe dummy address for last group
        const float4 xa_n = *(const float4*)(xp + tn);
        const float4 xb_n = *(const float4*)(xp + tn + 4);

        const float xs_arr[8] = {xa.x, xa.y, xa.z, xa.w, xb.x, xb.y, xb.z, xb.w};
        float y[8];

#pragma unroll
        for (int u = 0; u < 8; ++u) {
            const float xs = xs_arr[u];
            // Broadcast all four h components across the quad.
            const float h0 = qperm<0x00>(h);
            const float h1 = qperm<0x55>(h);
            const float h2 = qperm<0xAA>(h);
            const float h3 = qperm<0xFF>(h);

            float gi = fmaf(xs, wih_i, bi);
            gi = fmaf(wi0, h0, gi); gi = fmaf(wi1, h1, gi);
            gi = fmaf(wi2, h2, gi); gi = fmaf(wi3, h3, gi);

            float gf = fmaf(xs, wih_f, bf);
            gf = fmaf(wf0, h0, gf); gf = fmaf(wf1, h1, gf);
            gf = fmaf(wf2, h2, gf); gf = fmaf(wf3, h3, gf);

            float gg = fmaf(xs, wih_g, bg);
            gg = fmaf(wg0, h0, gg); gg = fmaf(wg1, h1, gg);
            gg = fmaf(wg2, h2, gg); gg = fmaf(wg3, h3, gg);

            float go = fmaf(xs, wih_o, bo);
            go = fmaf(wo0, h0, go); go = fmaf(wo1, h1, go);
            go = fmaf(wo2, h2, go); go = fmaf(wo3, h3, go);

            // Activations (scales already folded into gate pre-activations).
            const float ii = frcp(1.0f + fexp2(gi));
            const float ff = frcp(1.0f + fexp2(gf));
            const float oo = frcp(1.0f + fexp2(go));
            const float tg = fmaf(-2.0f, frcp(1.0f + fexp2(gg)), 1.0f);

            c = fmaf(ff, c, ii * tg);
            const float tc = fmaf(-2.0f, frcp(1.0f + fexp2(c * (2.0f * L2E))), 1.0f);
            h = oo * tc;

            // y_t = sum_j wlin_j * h_j + blin, reduced across the quad.
            float p = wlin * h;
            p += qperm<0xB1>(p);  // [1,0,3,2]
            p += qperm<0x4E>(p);  // [2,3,0,1]
            y[u] = p + blin;
        }

        if (j == 0) {
            *(float4*)(op + t)     = make_float4(y[0], y[1], y[2], y[3]);
            *(float4*)(op + t + 4) = make_float4(y[4], y[5], y[6], y[7]);
        }

        xa = xa_n;
        xb = xb_n;
    }
}

extern "C" void kernel_launch(void* const* d_in, const int* in_sizes, int n_in,
                              void* d_out, int out_size, void* d_ws, size_t ws_size,
                              hipStream_t stream) {
    const float* x     = (const float*)d_in[0];
    const float* W_ih  = (const float*)d_in[1];
    const float* W_hh  = (const float*)d_in[2];
    const float* b_ih  = (const float*)d_in[3];
    const float* b_hh  = (const float*)d_in[4];
    const float* W_lin = (const float*)d_in[5];
    const float* b_lin = (const float*)d_in[6];
    float* out = (float*)d_out;

    const int B = in_sizes[0] / TLEN;        // 4096
    const int threads = B * 4;               // quad per sequence
    const int block = 64;                    // 1 wave per block -> 256 blocks over 256 CUs
    const int grid = threads / block;

    lstm4_kernel<<<grid, block, 0, stream>>>(x, W_ih, W_hh, b_ih, b_hh,
                                             W_lin, b_lin, out);
}